// Round 8
// baseline (2223.380 us; speedup 1.0000x reference)
//
#include <hip/hip_runtime.h>

#define BB 128
#define TT 2048
#define DD 64
#define HH 128
#define OO 32
#define NB 16
#define SCALE 2.885390081777927f   // 2/ln2 folded into weights: tanh = 1-2*rcp(1+exp2(z))

typedef _Float16 f16x8 __attribute__((ext_vector_type(8)));
typedef __fp16   pk16x2 __attribute__((ext_vector_type(2)));
typedef float    f32x4 __attribute__((ext_vector_type(4)));

#define MFMA16(a,b,c) __builtin_amdgcn_mfma_f32_16x16x32_f16((a),(b),(c),0,0,0)

__device__ __forceinline__ f32x4 load4(const float* p){ return *(const f32x4*)p; }

// A-fragment for 16x16x32 (A[m=lane&15][k=(lane>>4)*8+j]), scaled on load.
__device__ __forceinline__ f16x8 afrag_s(const float* p, float s){
    float4 a = *(const float4*)p, b = *(const float4*)(p+4);
    f16x8 r;
    r[0]=(_Float16)(a.x*s); r[1]=(_Float16)(a.y*s); r[2]=(_Float16)(a.z*s); r[3]=(_Float16)(a.w*s);
    r[4]=(_Float16)(b.x*s); r[5]=(_Float16)(b.y*s); r[6]=(_Float16)(b.z*s); r[7]=(_Float16)(b.w*s);
    return r;
}

// tanh with z = SCALE*u pre-folded: e = 2^z = e^{2u}; tanh = 1 - 2/(1+e).
__device__ __forceinline__ float tanh_pre(float z){
#if __has_builtin(__builtin_amdgcn_exp2f)
    float e = __builtin_amdgcn_exp2f(z);
#else
    float e = exp2f(z);
#endif
    return __builtin_fmaf(-2.f, __builtin_amdgcn_rcpf(1.f + e), 1.f);
}

__device__ __forceinline__ unsigned pk2(float a, float b){
    union { pk16x2 h; unsigned u; } c;
    c.h = __builtin_amdgcn_cvt_pkrtz(a, b);
    return c.u;
}

// pack 8 f32 (two float4) into an f16x8 B-fragment (RTZ, same as h path).
__device__ __forceinline__ f16x8 xfrag(float4 a, float4 b){
    union { unsigned u[4]; f16x8 v; } c;
    c.u[0] = pk2(a.x, a.y); c.u[1] = pk2(a.z, a.w);
    c.u[2] = pk2(b.x, b.y); c.u[3] = pk2(b.z, b.w);
    return c.v;
}

// combined spin: min(f[0..3]) >= n1 && min(f[4..7]) >= n2.
// Flags start at -1 and only grow; negative needs are satisfied immediately.
__device__ __forceinline__ void wait2(const volatile int* f, int n1, int n2){
    for(;;){
        int a0=f[0], a1=f[1], a2=f[2], a3=f[3];
        int b0=f[4], b1=f[5], b2=f[6], b3=f[7];
        int ma = min(min(a0,a1), min(a2,a3));
        int mb = min(min(b0,b1), min(b2,b3));
        if (ma >= n1 && mb >= n2) break;
        __builtin_amdgcn_s_sleep(1);
    }
    asm volatile("" ::: "memory");
}

// ---------------------------------------------------------------------------
// scan v8: decoupled producer/consumer (no per-step barrier).
//   L1 group (waves 0-3): h1 recurrence + fused proj, h1 ring depth 4.
//     step t: wait minP1>=t-1 (peers) && minP2>=t-3 (ring slot free).
//   L2 group (waves 4-7): h2 recurrence + FC (waves 4,5), h2 ping-pong.
//     step u: wait minP1>=u (h1(u) ready) && minP2>=u-1 (peers).
//   Writers: ds_write data -> lgkmcnt(0) -> publish P[w] (lane 0).
// Bounded-ring pipeline, deadlock-free; phases drift so pipes overlap.
// ---------------------------------------------------------------------------
#define LSTR2 136               // halves per row; 272 B row stride (16B-aligned frags)
#define PHB   (NB*LSTR2*2)      // bytes per slot = 4352

#define L1STEP(T_, XS_) do {                                                  \
    const int t_ = (T_);                                                      \
    wait2(PF, t_ - 1, t_ - 3);                                                \
    const char* rp = (const char*)H1R + ((t_+3)&3)*PHB + n*272 + q*16;        \
    f16x8 bh1[4];                                                             \
    _Pragma("unroll")                                                         \
    for (int kt = 0; kt < 4; ++kt)                                            \
        bh1[kt] = *(const f16x8*)(rp + kt*64);                                \
    f16x8 xB0 = xfrag(XS_[0], XS_[1]);                                        \
    f16x8 xB1 = xfrag(XS_[2], XS_[3]);                                        \
    f32x4 z[2];                                                               \
    _Pragma("unroll")                                                         \
    for (int m = 0; m < 2; ++m){                                              \
        z[m] = bv0[m];                                                        \
        z[m] = MFMA16(Aih[m][0], xB0, z[m]);                                  \
        z[m] = MFMA16(Aih[m][1], xB1, z[m]);                                  \
    }                                                                         \
    _Pragma("unroll")                                                         \
    for (int kt = 0; kt < 4; ++kt)                                            \
        _Pragma("unroll")                                                     \
        for (int m = 0; m < 2; ++m)                                           \
            z[m] = MFMA16(A0[m][kt], bh1[kt], z[m]);                          \
    {   /* clamped x reload into the SAME named slots, distance 2 */          \
        const int tl = (t_ + 2 < TT) ? (t_ + 2) : (TT - 1);                   \
        const float* xq = xb + (size_t)tl*DD;                                 \
        XS_[0] = *(const float4*)(xq);                                        \
        XS_[1] = *(const float4*)(xq + 4);                                    \
        XS_[2] = *(const float4*)(xq + 32);                                   \
        XS_[3] = *(const float4*)(xq + 36);                                   \
    }                                                                         \
    {   char* wp = (char*)H1R + (t_&3)*PHB + n*272 + (w*2)*32 + q*8;          \
        _Pragma("unroll")                                                     \
        for (int m = 0; m < 2; ++m){                                          \
            uint2 v;                                                          \
            v.x = pk2(tanh_pre(z[m][0]), tanh_pre(z[m][1]));                  \
            v.y = pk2(tanh_pre(z[m][2]), tanh_pre(z[m][3]));                  \
            *(uint2*)(wp + m*32) = v;                                         \
        }                                                                     \
    }                                                                         \
    asm volatile("s_waitcnt lgkmcnt(0)" ::: "memory");                        \
    if (lane == 0) ((volatile int*)PF)[w] = t_;                               \
} while (0)

extern "C" __global__ void __launch_bounds__(512, 1)
scan_kernel(const float* __restrict__ x, const int* __restrict__ lengths,
            const float* __restrict__ W_ih0, const float* __restrict__ W_hh0,
            const float* __restrict__ b_ih0, const float* __restrict__ b_hh0,
            const float* __restrict__ W_ih1, const float* __restrict__ W_hh1,
            const float* __restrict__ b_ih1, const float* __restrict__ b_hh1,
            const float* __restrict__ W_fc,  const float* __restrict__ b_fc,
            float* __restrict__ out)
{
    const int tid  = threadIdx.x;
    const int w    = tid >> 6, lane = tid & 63;
    const int n    = lane & 15, q = lane >> 4;
    const int rbase= blockIdx.x * NB;

    __shared__ __align__(16) _Float16 H1R[4][NB][LSTR2];   // 4-slot h1 ring
    __shared__ __align__(16) _Float16 H2P[2][NB][LSTR2];   // h2 ping-pong
    __shared__ int PF[8];                                  // P1[0..3], P2[4..7]

    for (int idx = tid; idx < (6*NB*LSTR2)/2; idx += 512){
        if (idx < (4*NB*LSTR2)/2) ((unsigned*)H1R)[idx] = 0u;
        else ((unsigned*)H2P)[idx - (4*NB*LSTR2)/2] = 0u;
    }
    if (tid < 8) PF[tid] = -1;

    const int lenn = lengths[rbase + n];
    int mx = lenn;
    #pragma unroll
    for (int s = 1; s < 16; s <<= 1){ int o = __shfl_xor(mx, s, 64); mx = max(mx, o); }
    const int maxlen = __builtin_amdgcn_readfirstlane(mx);

    __syncthreads();

    if (w < 4){
        // ---- L1 waves: m-tiles {2w, 2w+1}; proj fused inline ----
        f16x8 A0[2][4], Aih[2][2];
        f32x4 bv0[2];
        #pragma unroll
        for (int m = 0; m < 2; ++m){
            const int row = (w*2 + m)*16 + n;
            #pragma unroll
            for (int kt = 0; kt < 4; ++kt)
                A0[m][kt] = afrag_s(W_hh0 + row*HH + kt*32 + q*8, SCALE);
            #pragma unroll
            for (int kt = 0; kt < 2; ++kt)
                Aih[m][kt] = afrag_s(W_ih0 + row*DD + kt*32 + q*8, SCALE);
            bv0[m] = (load4(b_ih0 + (w*2+m)*16 + q*4)
                    + load4(b_hh0 + (w*2+m)*16 + q*4)) * SCALE;
        }

        const float* xb = x + ((size_t)(rbase+n)*TT)*DD + q*8;

        float4 xe[4], xo[4];
        {
            const float* x0 = xb;
            const float* x1 = xb + DD;
            xe[0] = *(const float4*)(x0);      xe[1] = *(const float4*)(x0 + 4);
            xe[2] = *(const float4*)(x0 + 32); xe[3] = *(const float4*)(x0 + 36);
            xo[0] = *(const float4*)(x1);      xo[1] = *(const float4*)(x1 + 4);
            xo[2] = *(const float4*)(x1 + 32); xo[3] = *(const float4*)(x1 + 36);
        }

        for (int t0 = 0; t0 < maxlen; t0 += 2){
            L1STEP(t0, xe);
            if (t0 + 1 < maxlen) L1STEP(t0 + 1, xo);
        }
    } else {
        // ---- L2 waves: m-tiles {2wl, 2wl+1}; waves 4,5 add FC half wl ----
        const int wl = w - 4;
        const bool doFC = (wl < 2);
        const int f = wl & 1;
        f16x8 Ai[2][4], Ah[2][4];
        f32x4 b1v[2];
        #pragma unroll
        for (int m = 0; m < 2; ++m){
            const int row = (wl*2 + m)*16 + n;
            #pragma unroll
            for (int kt = 0; kt < 4; ++kt){
                Ai[m][kt] = afrag_s(W_ih1 + row*HH + kt*32 + q*8, SCALE);
                Ah[m][kt] = afrag_s(W_hh1 + row*HH + kt*32 + q*8, SCALE);
            }
            b1v[m] = (load4(b_ih1 + (wl*2+m)*16 + q*4)
                    + load4(b_hh1 + (wl*2+m)*16 + q*4)) * SCALE;
        }
        f16x8 Af[4];
        #pragma unroll
        for (int kt = 0; kt < 4; ++kt)
            Af[kt] = afrag_s(W_fc + (f*16 + n)*HH + kt*32 + q*8, 1.0f);
        const f32x4 bfv = load4(b_fc + f*16 + q*4);

        float* obase = out + ((size_t)(rbase+n)*TT)*OO + f*16 + q*4;

        for (int u = 0; u <= maxlen; ++u){
            const bool doRec = (u < maxlen);
            const int n1 = doRec ? u : (maxlen - 1);
            wait2(PF, n1, u - 1);
            const char* rp2 = (const char*)H2P + ((u+1)&1)*PHB + n*272 + q*16;
            f16x8 bh2[4];
            #pragma unroll
            for (int kt = 0; kt < 4; ++kt)
                bh2[kt] = *(const f16x8*)(rp2 + kt*64);
            f32x4 z[2];
            if (doRec){
                const char* rp1 = (const char*)H1R + (u&3)*PHB + n*272 + q*16;
                f16x8 bh1[4];
                #pragma unroll
                for (int kt = 0; kt < 4; ++kt)
                    bh1[kt] = *(const f16x8*)(rp1 + kt*64);
                f32x4 y[2];
                #pragma unroll
                for (int m = 0; m < 2; ++m){
                    z[m] = b1v[m];
                    y[m][0]=0.f; y[m][1]=0.f; y[m][2]=0.f; y[m][3]=0.f;
                }
                #pragma unroll
                for (int kt = 0; kt < 4; ++kt)
                    #pragma unroll
                    for (int m = 0; m < 2; ++m){
                        z[m] = MFMA16(Ai[m][kt], bh1[kt], z[m]);
                        y[m] = MFMA16(Ah[m][kt], bh2[kt], y[m]);
                    }
                #pragma unroll
                for (int m = 0; m < 2; ++m) z[m] += y[m];
            }
            if (doFC && u >= 1){
                f32x4 zf = bfv;
                #pragma unroll
                for (int kt = 0; kt < 4; ++kt) zf = MFMA16(Af[kt], bh2[kt], zf);
                if (u - 1 < lenn){
                    float4 sv; sv.x=zf[0]; sv.y=zf[1]; sv.z=zf[2]; sv.w=zf[3];
                    *(float4*)(obase + (size_t)(u-1)*OO) = sv;
                }
            }
            if (doRec){
                char* wp = (char*)H2P + (u&1)*PHB + n*272 + (wl*2)*32 + q*8;
                #pragma unroll
                for (int m = 0; m < 2; ++m){
                    uint2 v;
                    v.x = pk2(tanh_pre(z[m][0]), tanh_pre(z[m][1]));
                    v.y = pk2(tanh_pre(z[m][2]), tanh_pre(z[m][3]));
                    *(uint2*)(wp + m*32) = v;
                }
            }
            asm volatile("s_waitcnt lgkmcnt(0)" ::: "memory");
            if (lane == 0) ((volatile int*)PF)[4 + wl] = u;
        }
    }

    // ---- fused pad-fill tail: out[b][t][:] = b_fc for t >= lengths[b] ----
    {
        const int row  = tid >> 5;             // 0..15
        const int lr   = lengths[rbase + row];
        const int o4   = tid & 7;              // float4 index within 32 floats
        const int tpar = (tid >> 3) & 3;       // t offset (stride 4)
        const float4 bf4 = *(const float4*)(b_fc + o4*4);
        float* ob = out + ((size_t)(rbase+row)*TT)*OO + o4*4;
        for (int t = lr + tpar; t < TT; t += 4)
            *(float4*)(ob + (size_t)t*OO) = bf4;
    }
}

// ---------------------------------------------------------------------------
extern "C" void kernel_launch(void* const* d_in, const int* in_sizes, int n_in,
                              void* d_out, int out_size, void* d_ws, size_t ws_size,
                              hipStream_t stream)
{
    const float* x       = (const float*)d_in[0];
    const int*   lengths = (const int*)  d_in[1];
    const float* W_ih0   = (const float*)d_in[2];
    const float* W_hh0   = (const float*)d_in[3];
    const float* b_ih0   = (const float*)d_in[4];
    const float* b_hh0   = (const float*)d_in[5];
    const float* W_ih1   = (const float*)d_in[6];
    const float* W_hh1   = (const float*)d_in[7];
    const float* b_ih1   = (const float*)d_in[8];
    const float* b_hh1   = (const float*)d_in[9];
    const float* W_fc    = (const float*)d_in[10];
    const float* b_fc    = (const float*)d_in[11];

    scan_kernel<<<BB/NB, 512, 0, stream>>>(x, lengths, W_ih0, W_hh0,
                                           b_ih0, b_hh0,
                                           W_ih1, W_hh1, b_ih1, b_hh1,
                                           W_fc, b_fc, (float*)d_out);
}

// Round 9
// 1567.295 us; speedup vs baseline: 1.4186x; 1.4186x over previous
//
#include <hip/hip_runtime.h>

#define BB 128
#define TT 2048
#define DD 64
#define HH 128
#define OO 32
#define NB 16
#define SCALE 2.885390081777927f   // 2/ln2 folded into weights: tanh = 1-2*rcp(1+exp2(z))

typedef _Float16 f16x8 __attribute__((ext_vector_type(8)));
typedef __fp16   pk16x2 __attribute__((ext_vector_type(2)));
typedef float    f32x4 __attribute__((ext_vector_type(4)));

#define MFMA16(a,b,c) __builtin_amdgcn_mfma_f32_16x16x32_f16((a),(b),(c),0,0,0)

__device__ __forceinline__ f32x4 load4(const float* p){ return *(const f32x4*)p; }

// A-fragment for 16x16x32 (A[m=lane&15][k=(lane>>4)*8+j]), scaled on load.
__device__ __forceinline__ f16x8 afrag_s(const float* p, float s){
    float4 a = *(const float4*)p, b = *(const float4*)(p+4);
    f16x8 r;
    r[0]=(_Float16)(a.x*s); r[1]=(_Float16)(a.y*s); r[2]=(_Float16)(a.z*s); r[3]=(_Float16)(a.w*s);
    r[4]=(_Float16)(b.x*s); r[5]=(_Float16)(b.y*s); r[6]=(_Float16)(b.z*s); r[7]=(_Float16)(b.w*s);
    return r;
}

// tanh with z = SCALE*u pre-folded: e = 2^z = e^{2u}; tanh = 1 - 2/(1+e).
__device__ __forceinline__ float tanh_pre(float z){
#if __has_builtin(__builtin_amdgcn_exp2f)
    float e = __builtin_amdgcn_exp2f(z);
#else
    float e = exp2f(z);
#endif
    return __builtin_fmaf(-2.f, __builtin_amdgcn_rcpf(1.f + e), 1.f);
}

__device__ __forceinline__ unsigned pk2(float a, float b){
    union { pk16x2 h; unsigned u; } c;
    c.h = __builtin_amdgcn_cvt_pkrtz(a, b);
    return c.u;
}

// pack 8 f32 (two float4) into an f16x8 B-fragment (RTZ, same as h path).
__device__ __forceinline__ f16x8 xfrag(float4 a, float4 b){
    union { unsigned u[4]; f16x8 v; } c;
    c.u[0] = pk2(a.x, a.y); c.u[1] = pk2(a.z, a.w);
    c.u[2] = pk2(b.x, b.y); c.u[3] = pk2(b.z, b.w);
    return c.v;
}

// ---------------------------------------------------------------------------
// scan v9 = v7 with lag-2 cross-layer pipeline:
//   h1 ring depth 4 (slot p&3). L1 at phase p computes h1(p) (self-loop
//   read of h1(p-1) stays post-barrier, covered by reg-resident proj MFMAs).
//   L2 at phase p computes h2(u), u=p-2, using rh1 = h1(u) PRE-LOADED into
//   registers at the end of phase p-1 (slot stable: written at p-2).
//   Post-barrier, L2 issues only its h2 self-loop reads and starts the
//   z-chain immediately from rh1 registers. FC output row = p-3.
// 272B stride (single ds_read_b128, 2-way aliasing = free), one barrier/phase.
// ---------------------------------------------------------------------------
#define LSTR2 136               // halves per row; 272 B row stride
#define PHB   (NB*LSTR2*2)      // bytes per slot = 4352

#define L1PHASE(P_, XS_) do {                                                 \
    const int p_ = (P_);                                                      \
    const char* rp = (const char*)H1R + ((p_+3)&3)*PHB + n*272 + q*16;        \
    f16x8 bh1[4];                                                             \
    _Pragma("unroll")                                                         \
    for (int kt = 0; kt < 4; ++kt)                                            \
        bh1[kt] = *(const f16x8*)(rp + kt*64);                                \
    const bool doZ0 = (p_ < maxlen);                                          \
    f32x4 za[2], zb[2];                                                       \
    if (doZ0){                                                                \
        f16x8 xB0 = xfrag(XS_[0], XS_[1]);                                    \
        f16x8 xB1 = xfrag(XS_[2], XS_[3]);                                    \
        _Pragma("unroll")                                                     \
        for (int m = 0; m < 2; ++m){                                          \
            za[m] = bv0[m];                                                   \
            za[m] = MFMA16(Aih[m][0], xB0, za[m]);                            \
            zb[m][0]=0.f; zb[m][1]=0.f; zb[m][2]=0.f; zb[m][3]=0.f;           \
            zb[m] = MFMA16(Aih[m][1], xB1, zb[m]);                            \
        }                                                                     \
        _Pragma("unroll")                                                     \
        for (int m = 0; m < 2; ++m){                                          \
            za[m] = MFMA16(A0[m][0], bh1[0], za[m]);                          \
            zb[m] = MFMA16(A0[m][1], bh1[1], zb[m]);                          \
            za[m] = MFMA16(A0[m][2], bh1[2], za[m]);                          \
            zb[m] = MFMA16(A0[m][3], bh1[3], zb[m]);                          \
        }                                                                     \
    }                                                                         \
    {   /* unconditional clamped x reload into the SAME named slots */        \
        const int tl = (p_ + 2 < TT) ? (p_ + 2) : (TT - 1);                   \
        const float* xq = xb + (size_t)tl*DD;                                 \
        XS_[0] = *(const float4*)(xq);                                        \
        XS_[1] = *(const float4*)(xq + 4);                                    \
        XS_[2] = *(const float4*)(xq + 32);                                   \
        XS_[3] = *(const float4*)(xq + 36);                                   \
    }                                                                         \
    if (doZ0){                                                                \
        char* wp = (char*)H1R + (p_&3)*PHB + n*272 + (w*2)*32 + q*8;          \
        _Pragma("unroll")                                                     \
        for (int m = 0; m < 2; ++m){                                          \
            f32x4 zz = za[m] + zb[m];                                         \
            uint2 v;                                                          \
            v.x = pk2(tanh_pre(zz[0]), tanh_pre(zz[1]));                      \
            v.y = pk2(tanh_pre(zz[2]), tanh_pre(zz[3]));                      \
            *(uint2*)(wp + m*32) = v;                                         \
        }                                                                     \
    }                                                                         \
    asm volatile("s_waitcnt lgkmcnt(0)\n\ts_barrier" ::: "memory");           \
} while (0)

#define L2PHASE(P_) do {                                                      \
    const int p_ = (P_);                                                      \
    const int u_ = p_ - 2;                                                    \
    /* post-barrier: only the h2 self-loop read; h1 already in rh1 regs */    \
    const char* rp2 = (const char*)H2P + ((p_+1)&1)*PHB + n*272 + q*16;       \
    f16x8 bh2[4];                                                             \
    _Pragma("unroll")                                                         \
    for (int kt = 0; kt < 4; ++kt)                                            \
        bh2[kt] = *(const f16x8*)(rp2 + kt*64);                               \
    const bool doZ1 = (u_ >= 0) && (u_ < maxlen);                             \
    f32x4 za[2], zb[2], ya[2], yb[2];                                         \
    __builtin_amdgcn_s_setprio(1);                                            \
    if (doZ1){                                                                \
        /* z-chain first: pure register inputs, starts at barrier release */  \
        _Pragma("unroll")                                                     \
        for (int m = 0; m < 2; ++m){                                          \
            za[m] = b1v[m];                                                   \
            zb[m][0]=0.f; zb[m][1]=0.f; zb[m][2]=0.f; zb[m][3]=0.f;           \
            za[m] = MFMA16(Ai[m][0], rh1[0], za[m]);                          \
            zb[m] = MFMA16(Ai[m][1], rh1[1], zb[m]);                          \
            za[m] = MFMA16(Ai[m][2], rh1[2], za[m]);                          \
            zb[m] = MFMA16(Ai[m][3], rh1[3], zb[m]);                          \
        }                                                                     \
        _Pragma("unroll")                                                     \
        for (int m = 0; m < 2; ++m){                                          \
            ya[m][0]=0.f; ya[m][1]=0.f; ya[m][2]=0.f; ya[m][3]=0.f;           \
            yb[m] = ya[m];                                                    \
            ya[m] = MFMA16(Ah[m][0], bh2[0], ya[m]);                          \
            yb[m] = MFMA16(Ah[m][1], bh2[1], yb[m]);                          \
            ya[m] = MFMA16(Ah[m][2], bh2[2], ya[m]);                          \
            yb[m] = MFMA16(Ah[m][3], bh2[3], yb[m]);                          \
        }                                                                     \
    }                                                                         \
    if (doFC && p_ >= 3){                                                     \
        f32x4 zfa = bfv, zfb;                                                 \
        zfb[0]=0.f; zfb[1]=0.f; zfb[2]=0.f; zfb[3]=0.f;                       \
        zfa = MFMA16(Af[0], bh2[0], zfa);                                     \
        zfb = MFMA16(Af[1], bh2[1], zfb);                                     \
        zfa = MFMA16(Af[2], bh2[2], zfa);                                     \
        zfb = MFMA16(Af[3], bh2[3], zfb);                                     \
        if ((unsigned)(p_ - 3) < (unsigned)lenn){                             \
            f32x4 zf = zfa + zfb;                                             \
            float4 sv; sv.x=zf[0]; sv.y=zf[1]; sv.z=zf[2]; sv.w=zf[3];        \
            *(float4*)(obase + (size_t)(p_-3)*OO) = sv;                       \
        }                                                                     \
    }                                                                         \
    __builtin_amdgcn_s_setprio(0);                                            \
    if (doZ1){                                                                \
        char* wp = (char*)H2P + (p_&1)*PHB + n*272 + (wl*2)*32 + q*8;         \
        _Pragma("unroll")                                                     \
        for (int m = 0; m < 2; ++m){                                          \
            f32x4 zz = (za[m] + zb[m]) + (ya[m] + yb[m]);                     \
            uint2 v;                                                          \
            v.x = pk2(tanh_pre(zz[0]), tanh_pre(zz[1]));                      \
            v.y = pk2(tanh_pre(zz[2]), tanh_pre(zz[3]));                      \
            *(uint2*)(wp + m*32) = v;                                         \
        }                                                                     \
    }                                                                         \
    {   /* hoisted pre-barrier load: rh1 <- h1(p-1) for next phase */         \
        const char* rh = (const char*)H1R + ((p_+3)&3)*PHB + n*272 + q*16;    \
        _Pragma("unroll")                                                     \
        for (int kt = 0; kt < 4; ++kt)                                        \
            rh1[kt] = *(const f16x8*)(rh + kt*64);                            \
    }                                                                         \
    asm volatile("s_waitcnt lgkmcnt(0)\n\ts_barrier" ::: "memory");           \
} while (0)

extern "C" __global__ void __launch_bounds__(512, 1)
scan_kernel(const float* __restrict__ x, const int* __restrict__ lengths,
            const float* __restrict__ W_ih0, const float* __restrict__ W_hh0,
            const float* __restrict__ b_ih0, const float* __restrict__ b_hh0,
            const float* __restrict__ W_ih1, const float* __restrict__ W_hh1,
            const float* __restrict__ b_ih1, const float* __restrict__ b_hh1,
            const float* __restrict__ W_fc,  const float* __restrict__ b_fc,
            float* __restrict__ out)
{
    const int tid  = threadIdx.x;
    const int w    = tid >> 6, lane = tid & 63;
    const int n    = lane & 15, q = lane >> 4;
    const int rbase= blockIdx.x * NB;

    __shared__ __align__(16) _Float16 H1R[4][NB][LSTR2];   // h1 ring, depth 4
    __shared__ __align__(16) _Float16 H2P[2][NB][LSTR2];   // h2 ping-pong

    for (int idx = tid; idx < (6*NB*LSTR2)/2; idx += 512){
        if (idx < (4*NB*LSTR2)/2) ((unsigned*)H1R)[idx] = 0u;
        else ((unsigned*)H2P)[idx - (4*NB*LSTR2)/2] = 0u;
    }

    const int lenn = lengths[rbase + n];
    int mx = lenn;
    #pragma unroll
    for (int s = 1; s < 16; s <<= 1){ int o = __shfl_xor(mx, s, 64); mx = max(mx, o); }
    const int maxlen = __builtin_amdgcn_readfirstlane(mx);

    __syncthreads();

    if (w < 4){
        // ---- L1 waves: m-tiles {2w, 2w+1}; proj fused inline ----
        f16x8 A0[2][4], Aih[2][2];
        f32x4 bv0[2];
        #pragma unroll
        for (int m = 0; m < 2; ++m){
            const int row = (w*2 + m)*16 + n;
            #pragma unroll
            for (int kt = 0; kt < 4; ++kt)
                A0[m][kt] = afrag_s(W_hh0 + row*HH + kt*32 + q*8, SCALE);
            #pragma unroll
            for (int kt = 0; kt < 2; ++kt)
                Aih[m][kt] = afrag_s(W_ih0 + row*DD + kt*32 + q*8, SCALE);
            bv0[m] = (load4(b_ih0 + (w*2+m)*16 + q*4)
                    + load4(b_hh0 + (w*2+m)*16 + q*4)) * SCALE;
        }

        const float* xb = x + ((size_t)(rbase+n)*TT)*DD + q*8;

        float4 xe[4], xo[4];
        {
            const float* x0 = xb;
            const float* x1 = xb + DD;
            xe[0] = *(const float4*)(x0);      xe[1] = *(const float4*)(x0 + 4);
            xe[2] = *(const float4*)(x0 + 32); xe[3] = *(const float4*)(x0 + 36);
            xo[0] = *(const float4*)(x1);      xo[1] = *(const float4*)(x1 + 4);
            xo[2] = *(const float4*)(x1 + 32); xo[3] = *(const float4*)(x1 + 36);
        }

        for (int p0 = 0; p0 <= maxlen + 2; p0 += 2){
            L1PHASE(p0,     xe);
            L1PHASE(p0 + 1, xo);
        }
    } else {
        // ---- L2 waves: m-tiles {2wl, 2wl+1}; waves 4,5 add FC half wl ----
        const int wl = w - 4;
        const bool doFC = (wl < 2);
        const int f = wl & 1;
        f16x8 Ai[2][4], Ah[2][4];
        f32x4 b1v[2];
        #pragma unroll
        for (int m = 0; m < 2; ++m){
            const int row = (wl*2 + m)*16 + n;
            #pragma unroll
            for (int kt = 0; kt < 4; ++kt){
                Ai[m][kt] = afrag_s(W_ih1 + row*HH + kt*32 + q*8, SCALE);
                Ah[m][kt] = afrag_s(W_hh1 + row*HH + kt*32 + q*8, SCALE);
            }
            b1v[m] = (load4(b_ih1 + (wl*2+m)*16 + q*4)
                    + load4(b_hh1 + (wl*2+m)*16 + q*4)) * SCALE;
        }
        f16x8 Af[4];
        #pragma unroll
        for (int kt = 0; kt < 4; ++kt)
            Af[kt] = afrag_s(W_fc + (f*16 + n)*HH + kt*32 + q*8, 1.0f);
        const f32x4 bfv = load4(b_fc + f*16 + q*4);

        float* obase = out + ((size_t)(rbase+n)*TT)*OO + f*16 + q*4;

        f16x8 rh1[4];
        #pragma unroll
        for (int kt = 0; kt < 4; ++kt)
            #pragma unroll
            for (int j = 0; j < 8; ++j) rh1[kt][j] = (_Float16)0.f;

        for (int p0 = 0; p0 <= maxlen + 2; p0 += 2){
            L2PHASE(p0);
            L2PHASE(p0 + 1);
        }
    }

    // ---- fused pad-fill tail: out[b][t][:] = b_fc for t >= lengths[b] ----
    {
        const int row  = tid >> 5;             // 0..15
        const int lr   = lengths[rbase + row];
        const int o4   = tid & 7;              // float4 index within 32 floats
        const int tpar = (tid >> 3) & 3;       // t offset (stride 4)
        const float4 bf4 = *(const float4*)(b_fc + o4*4);
        float* ob = out + ((size_t)(rbase+row)*TT)*OO + o4*4;
        for (int t = lr + tpar; t < TT; t += 4)
            *(float4*)(ob + (size_t)t*OO) = bf4;
    }
}

// ---------------------------------------------------------------------------
extern "C" void kernel_launch(void* const* d_in, const int* in_sizes, int n_in,
                              void* d_out, int out_size, void* d_ws, size_t ws_size,
                              hipStream_t stream)
{
    const float* x       = (const float*)d_in[0];
    const int*   lengths = (const int*)  d_in[1];
    const float* W_ih0   = (const float*)d_in[2];
    const float* W_hh0   = (const float*)d_in[3];
    const float* b_ih0   = (const float*)d_in[4];
    const float* b_hh0   = (const float*)d_in[5];
    const float* W_ih1   = (const float*)d_in[6];
    const float* W_hh1   = (const float*)d_in[7];
    const float* b_ih1   = (const float*)d_in[8];
    const float* b_hh1   = (const float*)d_in[9];
    const float* W_fc    = (const float*)d_in[10];
    const float* b_fc    = (const float*)d_in[11];

    scan_kernel<<<BB/NB, 512, 0, stream>>>(x, lengths, W_ih0, W_hh0,
                                           b_ih0, b_hh0,
                                           W_ih1, W_hh1, b_ih1, b_hh1,
                                           W_fc, b_fc, (float*)d_out);
}